// Round 7
// baseline (597.925 us; speedup 1.0000x reference)
//
#include <hip/hip_runtime.h>
#include <hip/hip_bf16.h>
#include <hip/hip_fp16.h>

#define DI __device__ __forceinline__
typedef unsigned int uint;
typedef unsigned long long ull;
typedef __attribute__((ext_vector_type(2))) _Float16 v2h;
typedef __attribute__((ext_vector_type(2))) __fp16 v2hf;   // cvt_pkrtz return type

// ---------- helpers ----------
DI float bf2f(unsigned short b) { return __uint_as_float(((unsigned)b) << 16); }
DI float bf2f_lo(uint u) { return __uint_as_float(u << 16); }
DI float bf2f_hi(uint u) { return __uint_as_float(u & 0xffff0000u); }
DI float sigm(float x) { return 1.0f / (1.0f + expf(-x)); }

DI float ldf(const void* p, int i, int f32) {
  return f32 ? ((const float*)p)[i] : bf2f(((const unsigned short*)p)[i]);
}

// packed f16 dot2 with f32 accumulate (v_dot2_f32_f16)
DI float dot2(uint w, uint h, float acc) {
#if __has_builtin(__builtin_amdgcn_fdot2)
  return __builtin_amdgcn_fdot2(__builtin_bit_cast(v2h, w),
                                __builtin_bit_cast(v2h, h), acc, false);
#else
  __half2 a = __builtin_bit_cast(__half2, w), b = __builtin_bit_cast(__half2, h);
  acc = fmaf(__half2float(a.x), __half2float(b.x), acc);
  return fmaf(__half2float(a.y), __half2float(b.y), acc);
#endif
}

DI uint pack2(float a, float b) {
#if __has_builtin(__builtin_amdgcn_cvt_pkrtz)
  v2hf p = __builtin_amdgcn_cvt_pkrtz(a, b);
  return __builtin_bit_cast(uint, p);
#else
  __half2 p = __floats2half2_rn(a, b);
  return __builtin_bit_cast(uint, p);
#endif
}

// opaque register pins: forbid the allocator from rematerializing (re-loading)
// these values inside a loop — the asm is a redefinition a reload would skip.
DI void keep4(uint4& v) { asm volatile("" : "+v"(v.x), "+v"(v.y), "+v"(v.z), "+v"(v.w)); }
DI void keep2(uint2& v) { asm volatile("" : "+v"(v.x), "+v"(v.y)); }
DI void keep1(uint& v)  { asm volatile("" : "+v"(v)); }

// ---------- workspace layout (float offsets) ----------
constexpr int OFF_P    = 0;        // [64 tok][1000]
constexpr int OFF_S    = 64000;    // [2][32][500]
constexpr int OFF_SIM  = 96000;    // [12][32][32]
constexpr int OFF_A0   = 108288;   // [32][32][12]
constexpr int OFF_A1   = 120576;   // [16][16][128]
constexpr int OFF_A2   = 153344;   // [8][8][164]
constexpr int OFF_A3   = 163840;   // [4][4][192]
constexpr int OFF_A4   = 166912;   // [2][2][192]
constexpr int OFF_A5   = 167680;   // [128]
constexpr int OFF_WT1  = 167936;   // [128][9][12] f32
constexpr int OFF_WT2  = 181760;   // [164][9][128]
constexpr int OFF_WT3  = 370688;   // [192][9][164]
constexpr int OFF_WT4  = 654080;   // [192][9][192]
constexpr int OFF_WT5  = 985856;   // [128][9][192]
constexpr int OFF_WHH  = 1207040;  // padded f16 [1000][256]
constexpr int OFF_FLAG = 1335040;  // int flag (1 = inputs are f32)
constexpr int OFF_CB   = 1335048;  // 5 x 256 conv biases f32
constexpr int OFF_DNNW = 1336328;  // 16384
constexpr int OFF_DNNB = 1352712;  // 128
constexpr int OFF_OUTW = 1352840;  // 640
constexpr int OFF_OUTB = 1353480;  // 8
// end 1353488 floats = 5.41 MB

// ---------- kernel 0: dtype probe ----------
__global__ __launch_bounds__(1024) void k_mode(const uint4* __restrict__ w4,
                                               int* __restrict__ flag) {
  __shared__ int cnt;
  if (threadIdx.x == 0) cnt = 0;
  __syncthreads();
  int c = 0;
  for (int i = threadIdx.x; i < 8192; i += 1024) {
    uint4 v = w4[i];
    uint a[4] = {v.x, v.y, v.z, v.w};
#pragma unroll
    for (int q = 0; q < 4; ++q) {
      if ((a[q] & 0x00007F80u) == 0x00007F80u) c++;
      if ((a[q] & 0x7F800000u) == 0x7F800000u) c++;
    }
  }
  atomicAdd(&cnt, c);
  __syncthreads();
  if (threadIdx.x == 0) *flag = (cnt > 0) ? 1 : 0;
}

// ---------- kernel 1a: input projection as LDS-tiled GEMM ----------
__global__ __launch_bounds__(256) void k_pgemm(
    const int* __restrict__ x1, const int* __restrict__ x2,
    const void* __restrict__ emb, const void* __restrict__ wih,
    const void* __restrict__ bih, const void* __restrict__ bhh,
    float* __restrict__ P, const int* __restrict__ flagp) {
  int f32 = *flagp;
  __shared__ int toks[64];
  __shared__ __align__(16) float e_lds[64 * 102];
  __shared__ __align__(16) float w_lds[8 * 102];
  int tid = threadIdx.x, n = blockIdx.x;           // rows [8n, 8n+8)
  if (tid < 64) toks[tid] = (tid < 32) ? x1[tid] : x2[tid - 32];
  __syncthreads();
  int tok = tid & 63, r2 = tid >> 6;               // r2 in [0,4)
  int row0 = 8 * n + r2, row1 = row0 + 4;
  float a0 = 0.f, a1 = 0.f;
  for (int kc = 0; kc < 300; kc += 100) {
    for (int idx = tid; idx < 6400; idx += 256) {
      int tk = idx / 100, kk = idx - tk * 100;
      e_lds[tk * 102 + kk] = ldf(emb, toks[tk] * 300 + kc + kk, f32);
    }
    for (int idx = tid; idx < 800; idx += 256) {
      int rr = idx / 100, kk2 = idx - rr * 100;
      w_lds[rr * 102 + kk2] = ldf(wih, (8 * n + rr) * 300 + kc + kk2, f32);
    }
    __syncthreads();
    const float2* ep  = (const float2*)(e_lds + tok * 102);
    const float2* w0p = (const float2*)(w_lds + r2 * 102);
    const float2* w1p = (const float2*)(w_lds + (r2 + 4) * 102);
#pragma unroll 10
    for (int m = 0; m < 50; ++m) {
      float2 ev = ep[m];
      float2 wa = w0p[m], wb = w1p[m];
      a0 = fmaf(ev.x, wa.x, a0); a0 = fmaf(ev.y, wa.y, a0);
      a1 = fmaf(ev.x, wb.x, a1); a1 = fmaf(ev.y, wb.y, a1);
    }
    __syncthreads();
  }
  a0 += ldf(bih, row0, f32) + ldf(bhh, row0, f32);
  a1 += ldf(bih, row1, f32) + ldf(bhh, row1, f32);
  P[tok * 1000 + row0] = a0;
  P[tok * 1000 + row1] = a1;
}

// ---------- kernel 1b: weight prep (LDS-staged transposes, coalesced R+W) ----------
DI void cvt_arr(int gid, int stride, int n, float* dst, const void* src, int f32) {
  for (int i = gid; i < n; i += stride) dst[i] = ldf(src, i, f32);
}

template <int CI>
DI void oc_tr(int ocl, float* __restrict__ dst, const void* __restrict__ src,
              int f32, float* lds, int tid) {
  const int N = CI * 9;
  int base = ocl * N;
  for (int m = tid; m < N; m += 256) lds[m] = ldf(src, base + m, f32);  // coalesced
  __syncthreads();
  for (int j = tid; j < N; j += 256) {              // coalesced write, LDS stride-9 read
    int tap = j / CI, ci = j - tap * CI;
    dst[base + j] = lds[ci * 9 + tap];
  }
}

__global__ __launch_bounds__(256) void k_pwt(
    const void* __restrict__ whh,
    const void* __restrict__ cw1, const void* __restrict__ cw2, const void* __restrict__ cw3,
    const void* __restrict__ cw4, const void* __restrict__ cw5,
    const void* __restrict__ cb1, const void* __restrict__ cb2, const void* __restrict__ cb3,
    const void* __restrict__ cb4, const void* __restrict__ cb5,
    const void* __restrict__ dnnw, const void* __restrict__ dnnb,
    const void* __restrict__ outw, const void* __restrict__ outb,
    float* __restrict__ ws, __half* __restrict__ whh_h, const int* __restrict__ flagp) {
  int f32 = *flagp;
  __shared__ __align__(16) float lds[1728];   // max CI*9 = 192*9
  int b = blockIdx.x, tid = threadIdx.x;
  if (b < 128)      oc_tr<12>(b, ws + OFF_WT1, cw1, f32, lds, tid);
  else if (b < 292) oc_tr<128>(b - 128, ws + OFF_WT2, cw2, f32, lds, tid);
  else if (b < 484) oc_tr<164>(b - 292, ws + OFF_WT3, cw3, f32, lds, tid);
  else if (b < 676) oc_tr<192>(b - 484, ws + OFF_WT4, cw4, f32, lds, tid);
  else if (b < 804) oc_tr<192>(b - 676, ws + OFF_WT5, cw5, f32, lds, tid);
  else {
    int gid = (b - 804) * 256 + tid;
    const int stride = 64 * 256;
    // w_hh -> f16, rows padded to 256 halves (512 B aligned rows)
    for (int i = gid; i < 250000; i += stride) {
      int row = i / 250, col = i - row * 250;
      whh_h[row * 256 + col] = __float2half(ldf(whh, i, f32));
    }
    cvt_arr(gid, stride, 128, ws + OFF_CB + 0 * 256, cb1, f32);
    cvt_arr(gid, stride, 164, ws + OFF_CB + 1 * 256, cb2, f32);
    cvt_arr(gid, stride, 192, ws + OFF_CB + 2 * 256, cb3, f32);
    cvt_arr(gid, stride, 192, ws + OFF_CB + 3 * 256, cb4, f32);
    cvt_arr(gid, stride, 128, ws + OFF_CB + 4 * 256, cb5, f32);
    cvt_arr(gid, stride, 16384, ws + OFF_DNNW, dnnw, f32);
    cvt_arr(gid, stride, 128, ws + OFF_DNNB, dnnb, f32);
    cvt_arr(gid, stride, 640, ws + OFF_OUTW, outw, f32);
    cvt_arr(gid, stride, 5, ws + OFF_OUTB, outb, f32);
  }
}

// ---------- kernel 2: recurrent LSTM, 4 blocks (sentence x direction) ----------
// 1024 threads, 1 gate-row/thread; weight split sized for the 128-VGPR cap
// (1024 thr => 4 waves/SIMD => 128 VGPRs, declared via launch_bounds(1024,4)):
//   k 0..191   : 96 half2-VGPRs, asm-pinned (round-6: compiler rematerialized
//                these loads in-loop at VGPR_Count=64 -> 110 us of L2 traffic)
//   k 192..219 : 14 half2/row in LDS
//   k 220..249 : 15 half2 hoisted + pinned
__global__ __launch_bounds__(1024, 4) void k_lstm(
    const float* __restrict__ P_all, const __half* __restrict__ Wp,
    float* __restrict__ S) {
  __shared__ __align__(16) uint2 wl[7][1000];   // 56000 B
  __shared__ __align__(16) uint h2[128];        // packed h (125 used)
  __shared__ __align__(16) float gates[1000];
  int tid = threadIdx.x;
  int r = blockIdx.x, s = r >> 1, rev = r & 1;
  bool act = tid < 1000;
  int rowi = act ? tid : 999;                   // clamp: uniform loads, no OOB
  const uint* wrow = (const uint*)(Wp + rowi * 256);

  uint4 wq[24];
  uint2 ta; uint4 tb, tc, td; uint te;
  {
    const uint4* w4 = (const uint4*)wrow;
#pragma unroll
    for (int j = 0; j < 24; ++j) wq[j] = w4[j];
    ta = *(const uint2*)(wrow + 110);
    tb = *(const uint4*)(wrow + 112);
    tc = *(const uint4*)(wrow + 116);
    td = *(const uint4*)(wrow + 120);
    te = wrow[124];
  }
  if (act) {
    const uint2* w2 = (const uint2*)wrow;
#pragma unroll
    for (int j = 0; j < 7; ++j) wl[j][tid] = w2[48 + j];
  }
#pragma unroll
  for (int j = 0; j < 24; ++j) keep4(wq[j]);
  keep2(ta); keep4(tb); keep4(tc); keep4(td); keep1(te);

  if (tid < 128) h2[tid] = 0u;
  float c = 0.0f;
  __syncthreads();

  const float* P = P_all + s * 32000;
#pragma unroll 1
  for (int t = 0; t < 32; ++t) {
    int tp = rev ? (31 - t) : t;
    {
      float acc = P[tp * 1000 + rowi];
      const uint4* h4 = (const uint4*)h2;
#pragma unroll
      for (int j = 0; j < 24; ++j) {            // k = 0..191 from pinned VGPRs
        uint4 hv = h4[j];
        acc = dot2(wq[j].x, hv.x, acc);
        acc = dot2(wq[j].y, hv.y, acc);
        acc = dot2(wq[j].z, hv.z, acc);
        acc = dot2(wq[j].w, hv.w, acc);
      }
#pragma unroll
      for (int j = 0; j < 7; ++j) {             // k = 192..219 from LDS
        uint2 wv = wl[j][rowi];
        acc = dot2(wv.x, h2[96 + 2 * j], acc);
        acc = dot2(wv.y, h2[97 + 2 * j], acc);
      }
      acc = dot2(ta.x, h2[110], acc);           // k = 220..249 from pinned VGPRs
      acc = dot2(ta.y, h2[111], acc);
      acc = dot2(tb.x, h2[112], acc);
      acc = dot2(tb.y, h2[113], acc);
      acc = dot2(tb.z, h2[114], acc);
      acc = dot2(tb.w, h2[115], acc);
      acc = dot2(tc.x, h2[116], acc);
      acc = dot2(tc.y, h2[117], acc);
      acc = dot2(tc.z, h2[118], acc);
      acc = dot2(tc.w, h2[119], acc);
      acc = dot2(td.x, h2[120], acc);
      acc = dot2(td.y, h2[121], acc);
      acc = dot2(td.z, h2[122], acc);
      acc = dot2(td.w, h2[123], acc);
      acc = dot2(te,   h2[124], acc);
      if (act) gates[tid] = acc;
    }
    __syncthreads();
    if (tid < 250) {
      float gi = gates[tid], gf = gates[250 + tid];
      float gg = gates[500 + tid], go = gates[750 + tid];
      c = sigm(gf) * c + sigm(gi) * tanhf(gg);
      float hn = sigm(go) * tanhf(c);
      S[(s * 32 + t) * 500 + rev * 250 + tid] = hn;
      float ho = __shfl_down(hn, 1);
      if ((tid & 1) == 0) h2[tid >> 1] = pack2(hn, ho);
    }
    __syncthreads();
  }
}

// ---------- kernel 3: similarity cube, one wave per (i,j) ----------
__global__ __launch_bounds__(64) void k_sim(const float* __restrict__ S,
                                            float* __restrict__ SIM) {
  int i = blockIdx.x >> 5, j = blockIdx.x & 31, l = threadIdx.x;
  const float* a = S + i * 500;
  const float* bv = S + 16000 + j * 500;
  float d[10];
#pragma unroll
  for (int v = 0; v < 10; ++v) d[v] = 0.0f;
  for (int k = l; k < 250; k += 64) {
    float af = a[k], ab = a[250 + k], bf = bv[k], bb = bv[250 + k];
    d[0] = fmaf(af, bf, d[0]);  d[1] = fmaf(ab, bb, d[1]);
    d[2] = fmaf(af, bb, d[2]);  d[3] = fmaf(ab, bf, d[3]);
    d[4] = fmaf(af, af, d[4]);  d[5] = fmaf(ab, ab, d[5]);
    d[6] = fmaf(af, ab, d[6]);  d[7] = fmaf(bf, bf, d[7]);
    d[8] = fmaf(bb, bb, d[8]);  d[9] = fmaf(bf, bb, d[9]);
  }
#pragma unroll
  for (int v = 0; v < 10; ++v)
    for (int off = 32; off > 0; off >>= 1) d[v] += __shfl_down(d[v], off);
  if (l == 0) {
    float dff = d[0], dbb = d[1], dfb = d[2], dbf = d[3];
    float nf1 = d[4], nb1 = d[5], c1 = d[6], nf2 = d[7], nb2 = d[8], c2 = d[9];
    int p = i * 32 + j;
    float dot = dff + dbb, n1f = nf1 + nb1, n2f = nf2 + nb2;
    SIM[0 * 1024 + p] = dot;
    SIM[1 * 1024 + p] = dot / (sqrtf(n1f) * sqrtf(n2f) + 1e-8f);
    SIM[2 * 1024 + p] = sqrtf(fmaxf(n1f + n2f - 2.0f * dot, 0.0f));
    SIM[3 * 1024 + p] = dff;
    SIM[4 * 1024 + p] = dff / (sqrtf(nf1) * sqrtf(nf2) + 1e-8f);
    SIM[5 * 1024 + p] = sqrtf(fmaxf(nf1 + nf2 - 2.0f * dff, 0.0f));
    SIM[6 * 1024 + p] = dbb;
    SIM[7 * 1024 + p] = dbb / (sqrtf(nb1) * sqrtf(nb2) + 1e-8f);
    SIM[8 * 1024 + p] = sqrtf(fmaxf(nb1 + nb2 - 2.0f * dbb, 0.0f));
    float dsum = dff + dbb + dfb + dbf;
    float ns1 = n1f + 2.0f * c1, ns2 = n2f + 2.0f * c2;
    SIM[9 * 1024 + p] = dsum;
    SIM[10 * 1024 + p] = dsum / (sqrtf(ns1) * sqrtf(ns2) + 1e-8f);
    SIM[11 * 1024 + p] = sqrtf(fmaxf(ns1 + ns2 - 2.0f * dsum, 0.0f));
  }
}

// ---------- kernel 4: top-64 greedy match (both channels in one sort cadence) ----------
__global__ __launch_bounds__(1024) void k_greedy(const float* __restrict__ SIM,
                                                 float* __restrict__ A0) {
  __shared__ ull keys0[1024], keys1[1024];
  __shared__ unsigned char sel[1024];
  int t = threadIdx.x;
  sel[t] = 0;
  {
    float v0 = SIM[9 * 1024 + t], v1 = SIM[10 * 1024 + t];
    uint u0 = __float_as_uint(v0);
    u0 = (u0 & 0x80000000u) ? ~u0 : (u0 | 0x80000000u);
    uint u1 = __float_as_uint(v1);
    u1 = (u1 & 0x80000000u) ? ~u1 : (u1 | 0x80000000u);
    keys0[t] = (((ull)u0) << 32) | (uint)(1023 - t);
    keys1[t] = (((ull)u1) << 32) | (uint)(1023 - t);
  }
  __syncthreads();
  for (int k = 2; k <= 1024; k <<= 1) {
    for (int j = k >> 1; j > 0; j >>= 1) {
      int ixj = t ^ j;
      if (ixj > t) {
        bool desc = ((t & k) == 0);
        ull a = keys0[t], b2 = keys0[ixj];
        if ((a < b2) == desc) { keys0[t] = b2; keys0[ixj] = a; }
        ull c2 = keys1[t], d2 = keys1[ixj];
        if ((c2 < d2) == desc) { keys1[t] = d2; keys1[ixj] = c2; }
      }
      __syncthreads();
    }
  }
  if (t == 0 || t == 512) {                       // two serial greedies, parallel waves
    const ull* ks = (t == 0) ? keys0 : keys1;
    uint m1 = 0, m2 = 0;
    for (int n = 0; n < 64; ++n) {
      int flat = 1023 - (int)(ks[n] & 0xFFFFFFFFu);
      int p1 = flat >> 5, p2 = flat & 31;
      if (!((m1 >> p1) & 1u) && !((m2 >> p2) & 1u)) {
        m1 |= 1u << p1; m2 |= 1u << p2; sel[flat] = 1;   // benign same-value race
      }
    }
  }
  __syncthreads();
  float fac = sel[t] ? 1.0f : 0.1f;
#pragma unroll
  for (int cidx = 0; cidx < 12; ++cidx)
    A0[t * 12 + cidx] = SIM[cidx * 1024 + t] * fac;  // channels-last [i][j][c]
}

// ---------- conv kernels (channels-last, fused relu+2x2 maxpool) ----------
template <int CIN, int CP, int COUT, int WIN, int TILESX, int G>
__global__ __launch_bounds__(256) void k_conv_tiled(
    const float* __restrict__ in, const float* __restrict__ wt,
    const float* __restrict__ bias, float* __restrict__ out) {
  __shared__ __align__(16) float lin[100 * CP];  // 10x10 halo tile
  __shared__ float pbuf[G * 64];
  int tid = threadIdx.x, b = blockIdx.x;
  const int TILES = TILESX * TILESX;
  int tile = b % TILES, ocg = b / TILES;
  int ty = tile / TILESX, tx = tile % TILESX;
  int oc0 = ocg * G;
  const int NQ = 25 * CIN;
  for (int m = tid; m < NQ; m += 256) {
    int pxy = m / (CIN / 4), cq = m - pxy * (CIN / 4);
    int py = pxy / 10, px = pxy - py * 10;
    int gy = ty * 8 + py - 1, gx = tx * 8 + px - 1;
    float4 v = make_float4(0.f, 0.f, 0.f, 0.f);
    if (gy >= 0 && gy < WIN && gx >= 0 && gx < WIN)
      v = *(const float4*)(in + (gy * WIN + gx) * CIN + 4 * cq);
    *(float4*)(lin + (py * 10 + px) * CP + 4 * cq) = v;
  }
  __syncthreads();
  int px = tid & 63, ocl = tid >> 6;
  int py2 = px >> 3, px2 = px & 7;
  const int G4 = G / 4;
  float acc[G4];
  int ocw[G4];
#pragma unroll
  for (int m = 0; m < G4; ++m) {
    int oc = oc0 + ocl + 4 * m;
    ocw[m] = (oc < COUT) ? oc : (COUT - 1);
    acc[m] = (oc < COUT) ? bias[oc] : 0.0f;
  }
#pragma unroll
  for (int tap = 0; tap < 9; ++tap) {
    int ky = tap / 3, kx = tap % 3;
    const float* ibase = lin + ((py2 + ky) * 10 + (px2 + kx)) * CP;
#pragma unroll 4
    for (int cq = 0; cq < CIN / 4; ++cq) {
      float4 iv = *(const float4*)(ibase + 4 * cq);
#pragma unroll
      for (int m = 0; m < G4; ++m) {
        float4 wv = *(const float4*)(wt + (ocw[m] * 9 + tap) * CIN + 4 * cq);
        acc[m] = fmaf(iv.x, wv.x, fmaf(iv.y, wv.y, fmaf(iv.z, wv.z, fmaf(iv.w, wv.w, acc[m]))));
      }
    }
  }
#pragma unroll
  for (int m = 0; m < G4; ++m)
    pbuf[(ocl + 4 * m) * 64 + px] = fmaxf(acc[m], 0.0f);
  __syncthreads();
  if (tid < G * 16) {
    int ocl2 = tid >> 4, q = tid & 15;
    int qy = q >> 2, qx = q & 3;
    const float* pb = pbuf + ocl2 * 64 + qy * 16 + qx * 2;
    float v = fmaxf(fmaxf(pb[0], pb[1]), fmaxf(pb[8], pb[9]));
    int oc = oc0 + ocl2;
    if (oc < COUT) {
      int gy = ty * 4 + qy, gx = tx * 4 + qx;
      out[(gy * (WIN / 2) + gx) * COUT + oc] = v;
    }
  }
}

template <int CIN, int CP, int COUT, int HW, int G>
__global__ __launch_bounds__(256) void k_conv_small(
    const float* __restrict__ in, const float* __restrict__ wt,
    const float* __restrict__ bias, float* __restrict__ out) {
  __shared__ __align__(16) float lin[HW * HW * CP];
  __shared__ float pbuf[G * HW * HW];
  int tid = threadIdx.x;
  int oc0 = blockIdx.x * G;
  const int NPX = HW * HW;
  const int NQ = NPX * CIN / 4;
  for (int m = tid; m < NQ; m += 256) {
    int pxy = m / (CIN / 4), cq = m - pxy * (CIN / 4);
    float4 v = *(const float4*)(in + pxy * CIN + 4 * cq);
    *(float4*)(lin + pxy * CP + 4 * cq) = v;
  }
  __syncthreads();
  int px = tid % NPX, ocl = tid / NPX;
  int py = px / HW, pxx = px % HW;
  int oc = oc0 + ocl;
  float acc = bias[oc];
#pragma unroll
  for (int tap = 0; tap < 9; ++tap) {
    int yy = py + tap / 3 - 1, xx = pxx + tap % 3 - 1;
    if (yy >= 0 && yy < HW && xx >= 0 && xx < HW) {
      const float* ibase = lin + (yy * HW + xx) * CP;
      const float* wbase = wt + (oc * 9 + tap) * CIN;
#pragma unroll 4
      for (int cq = 0; cq < CIN / 4; ++cq) {
        float4 iv = *(const float4*)(ibase + 4 * cq);
        float4 wv = *(const float4*)(wbase + 4 * cq);
        acc = fmaf(iv.x, wv.x, fmaf(iv.y, wv.y, fmaf(iv.z, wv.z, fmaf(iv.w, wv.w, acc))));
      }
    }
  }
  pbuf[ocl * NPX + px] = fmaxf(acc, 0.0f);
  __syncthreads();
  const int HW2 = HW / 2;
  if (tid < G * HW2 * HW2) {
    int ocl2 = tid / (HW2 * HW2), q = tid % (HW2 * HW2);
    int qy = q / HW2, qx = q % HW2;
    const float* pb = pbuf + ocl2 * NPX + (2 * qy) * HW + 2 * qx;
    float v = fmaxf(fmaxf(pb[0], pb[1]), fmaxf(pb[HW], pb[HW + 1]));
    out[(qy * HW2 + qx) * COUT + oc0 + ocl2] = v;
  }
}

// ---------- kernel 10: dense head ----------
__global__ __launch_bounds__(256) void k_fc(
    const float* __restrict__ A5,
    const float* __restrict__ dnnw, const float* __restrict__ dnnb,
    const float* __restrict__ outw, const float* __restrict__ outb,
    const int* __restrict__ flagp, void* __restrict__ outp) {
  __shared__ __align__(16) float v[128], u[128];
  int t = threadIdx.x;
  if (t < 128) v[t] = A5[t];
  __syncthreads();
  if (t < 128) {
    float acc = dnnb[t];
    const float* wr = dnnw + t * 128;
#pragma unroll 8
    for (int k = 0; k < 128; ++k) acc = fmaf(wr[k], v[k], acc);
    u[t] = fmaxf(acc, 0.0f);
  }
  __syncthreads();
  if (t < 5) {
    float acc = outb[t];
    const float* wr = outw + t * 128;
#pragma unroll 8
    for (int k = 0; k < 128; ++k) acc = fmaf(wr[k], u[k], acc);
    if (*flagp) ((float*)outp)[t] = acc;
    else ((__hip_bfloat16*)outp)[t] = __float2bfloat16(acc);
  }
}

// ---------- launch ----------
extern "C" void kernel_launch(void* const* d_in, const int* in_sizes, int n_in,
                              void* d_out, int out_size, void* d_ws, size_t ws_size,
                              hipStream_t stream) {
  const int* x1 = (const int*)d_in[0];
  const int* x2 = (const int*)d_in[1];

  float* ws = (float*)d_ws;
  __half* whh_h = (__half*)(ws + OFF_WHH);
  int* flagp = (int*)(ws + OFF_FLAG);

  k_mode<<<1, 1024, 0, stream>>>((const uint4*)d_in[4], flagp);
  k_pgemm<<<125, 256, 0, stream>>>(x1, x2, d_in[2], d_in[3], d_in[5], d_in[6],
                                   ws + OFF_P, flagp);
  k_pwt<<<868, 256, 0, stream>>>(d_in[4],
      d_in[7], d_in[9], d_in[11], d_in[13], d_in[15],
      d_in[8], d_in[10], d_in[12], d_in[14], d_in[16],
      d_in[17], d_in[18], d_in[19], d_in[20],
      ws, whh_h, flagp);
  k_lstm<<<4, 1024, 0, stream>>>(ws + OFF_P, whh_h, ws + OFF_S);
  k_sim<<<1024, 64, 0, stream>>>(ws + OFF_S, ws + OFF_SIM);
  k_greedy<<<1, 1024, 0, stream>>>(ws + OFF_SIM, ws + OFF_A0);
  k_conv_tiled<12, 12, 128, 32, 4, 8><<<256, 256, 0, stream>>>(ws + OFF_A0, ws + OFF_WT1, ws + OFF_CB + 0 * 256, ws + OFF_A1);
  k_conv_tiled<128, 132, 164, 16, 2, 8><<<84, 256, 0, stream>>>(ws + OFF_A1, ws + OFF_WT2, ws + OFF_CB + 1 * 256, ws + OFF_A2);
  k_conv_small<164, 164, 192, 8, 4><<<48, 256, 0, stream>>>(ws + OFF_A2, ws + OFF_WT3, ws + OFF_CB + 2 * 256, ws + OFF_A3);
  k_conv_small<192, 196, 192, 4, 16><<<12, 256, 0, stream>>>(ws + OFF_A3, ws + OFF_WT4, ws + OFF_CB + 3 * 256, ws + OFF_A4);
  k_conv_small<192, 196, 128, 2, 64><<<2, 256, 0, stream>>>(ws + OFF_A4, ws + OFF_WT5, ws + OFF_CB + 4 * 256, ws + OFF_A5);
  k_fc<<<1, 256, 0, stream>>>(ws + OFF_A5, ws + OFF_DNNW, ws + OFF_DNNB,
                              ws + OFF_OUTW, ws + OFF_OUTB, flagp, d_out);
}

// Round 8
// 548.953 us; speedup vs baseline: 1.0892x; 1.0892x over previous
//
#include <hip/hip_runtime.h>
#include <hip/hip_bf16.h>
#include <hip/hip_fp16.h>

#define DI __device__ __forceinline__
typedef unsigned int uint;
typedef unsigned long long ull;
typedef __attribute__((ext_vector_type(2))) _Float16 v2h;
typedef __attribute__((ext_vector_type(2))) __fp16 v2hf;   // cvt_pkrtz return type

// ---------- helpers ----------
DI float bf2f(unsigned short b) { return __uint_as_float(((unsigned)b) << 16); }
DI float bf2f_lo(uint u) { return __uint_as_float(u << 16); }
DI float bf2f_hi(uint u) { return __uint_as_float(u & 0xffff0000u); }
DI float sigm(float x) { return 1.0f / (1.0f + expf(-x)); }

DI float ldf(const void* p, int i, int f32) {
  return f32 ? ((const float*)p)[i] : bf2f(((const unsigned short*)p)[i]);
}

// packed f16 dot2 with f32 accumulate (v_dot2_f32_f16)
DI float dot2(uint w, uint h, float acc) {
#if __has_builtin(__builtin_amdgcn_fdot2)
  return __builtin_amdgcn_fdot2(__builtin_bit_cast(v2h, w),
                                __builtin_bit_cast(v2h, h), acc, false);
#else
  __half2 a = __builtin_bit_cast(__half2, w), b = __builtin_bit_cast(__half2, h);
  acc = fmaf(__half2float(a.x), __half2float(b.x), acc);
  return fmaf(__half2float(a.y), __half2float(b.y), acc);
#endif
}

DI uint pack2(float a, float b) {
#if __has_builtin(__builtin_amdgcn_cvt_pkrtz)
  v2hf p = __builtin_amdgcn_cvt_pkrtz(a, b);
  return __builtin_bit_cast(uint, p);
#else
  __half2 p = __floats2half2_rn(a, b);
  return __builtin_bit_cast(uint, p);
#endif
}

// opaque register pin: forbids rematerialization of held values inside loops
DI void keep4(uint4& v) { asm volatile("" : "+v"(v.x), "+v"(v.y), "+v"(v.z), "+v"(v.w)); }

// ---------- workspace layout (float offsets) ----------
constexpr int OFF_P    = 0;        // [64 tok][1000]
constexpr int OFF_S    = 64000;    // [2][32][500]
constexpr int OFF_SIM  = 96000;    // [12][32][32]
constexpr int OFF_A0   = 108288;   // [32][32][12]
constexpr int OFF_A1   = 120576;   // [16][16][128]
constexpr int OFF_A2   = 153344;   // [8][8][164]
constexpr int OFF_A3   = 163840;   // [4][4][192]
constexpr int OFF_A4   = 166912;   // [2][2][192]
constexpr int OFF_A5   = 167680;   // [128]
constexpr int OFF_WT1  = 167936;   // [128][9][12] f32
constexpr int OFF_WT2  = 181760;   // [164][9][128]
constexpr int OFF_WT3  = 370688;   // [192][9][164]
constexpr int OFF_WT4  = 654080;   // [192][9][192]
constexpr int OFF_WT5  = 985856;   // [128][9][192]
constexpr int OFF_WHH  = 1207040;  // padded f16 [1000][256]
constexpr int OFF_FLAG = 1335040;  // int flag (1 = inputs are f32)
constexpr int OFF_CB   = 1335048;  // 5 x 256 conv biases f32
constexpr int OFF_DNNW = 1336328;  // 16384
constexpr int OFF_DNNB = 1352712;  // 128
constexpr int OFF_OUTW = 1352840;  // 640
constexpr int OFF_OUTB = 1353480;  // 8
// end 1353488 floats = 5.41 MB

// ---------- kernel 0: dtype probe ----------
__global__ __launch_bounds__(1024) void k_mode(const uint4* __restrict__ w4,
                                               int* __restrict__ flag) {
  __shared__ int cnt;
  if (threadIdx.x == 0) cnt = 0;
  __syncthreads();
  int c = 0;
  for (int i = threadIdx.x; i < 8192; i += 1024) {
    uint4 v = w4[i];
    uint a[4] = {v.x, v.y, v.z, v.w};
#pragma unroll
    for (int q = 0; q < 4; ++q) {
      if ((a[q] & 0x00007F80u) == 0x00007F80u) c++;
      if ((a[q] & 0x7F800000u) == 0x7F800000u) c++;
    }
  }
  atomicAdd(&cnt, c);
  __syncthreads();
  if (threadIdx.x == 0) *flag = (cnt > 0) ? 1 : 0;
}

// ---------- kernel 1a: input projection as LDS-tiled GEMM ----------
__global__ __launch_bounds__(256) void k_pgemm(
    const int* __restrict__ x1, const int* __restrict__ x2,
    const void* __restrict__ emb, const void* __restrict__ wih,
    const void* __restrict__ bih, const void* __restrict__ bhh,
    float* __restrict__ P, const int* __restrict__ flagp) {
  int f32 = *flagp;
  __shared__ int toks[64];
  __shared__ __align__(16) float e_lds[64 * 102];
  __shared__ __align__(16) float w_lds[8 * 102];
  int tid = threadIdx.x, n = blockIdx.x;           // rows [8n, 8n+8)
  if (tid < 64) toks[tid] = (tid < 32) ? x1[tid] : x2[tid - 32];
  __syncthreads();
  int tok = tid & 63, r2 = tid >> 6;               // r2 in [0,4)
  int row0 = 8 * n + r2, row1 = row0 + 4;
  float a0 = 0.f, a1 = 0.f;
  for (int kc = 0; kc < 300; kc += 100) {
    for (int idx = tid; idx < 6400; idx += 256) {
      int tk = idx / 100, kk = idx - tk * 100;
      e_lds[tk * 102 + kk] = ldf(emb, toks[tk] * 300 + kc + kk, f32);
    }
    for (int idx = tid; idx < 800; idx += 256) {
      int rr = idx / 100, kk2 = idx - rr * 100;
      w_lds[rr * 102 + kk2] = ldf(wih, (8 * n + rr) * 300 + kc + kk2, f32);
    }
    __syncthreads();
    const float2* ep  = (const float2*)(e_lds + tok * 102);
    const float2* w0p = (const float2*)(w_lds + r2 * 102);
    const float2* w1p = (const float2*)(w_lds + (r2 + 4) * 102);
#pragma unroll 10
    for (int m = 0; m < 50; ++m) {
      float2 ev = ep[m];
      float2 wa = w0p[m], wb = w1p[m];
      a0 = fmaf(ev.x, wa.x, a0); a0 = fmaf(ev.y, wa.y, a0);
      a1 = fmaf(ev.x, wb.x, a1); a1 = fmaf(ev.y, wb.y, a1);
    }
    __syncthreads();
  }
  a0 += ldf(bih, row0, f32) + ldf(bhh, row0, f32);
  a1 += ldf(bih, row1, f32) + ldf(bhh, row1, f32);
  P[tok * 1000 + row0] = a0;
  P[tok * 1000 + row1] = a1;
}

// ---------- kernel 1b: weight prep (LDS-staged transposes, coalesced R+W) ----------
DI void cvt_arr(int gid, int stride, int n, float* dst, const void* src, int f32) {
  for (int i = gid; i < n; i += stride) dst[i] = ldf(src, i, f32);
}

template <int CI>
DI void oc_tr(int ocl, float* __restrict__ dst, const void* __restrict__ src,
              int f32, float* lds, int tid) {
  const int N = CI * 9;
  int base = ocl * N;
  for (int m = tid; m < N; m += 256) lds[m] = ldf(src, base + m, f32);  // coalesced
  __syncthreads();
  for (int j = tid; j < N; j += 256) {              // coalesced write, LDS stride-9 read
    int tap = j / CI, ci = j - tap * CI;
    dst[base + j] = lds[ci * 9 + tap];
  }
}

__global__ __launch_bounds__(256) void k_pwt(
    const void* __restrict__ whh,
    const void* __restrict__ cw1, const void* __restrict__ cw2, const void* __restrict__ cw3,
    const void* __restrict__ cw4, const void* __restrict__ cw5,
    const void* __restrict__ cb1, const void* __restrict__ cb2, const void* __restrict__ cb3,
    const void* __restrict__ cb4, const void* __restrict__ cb5,
    const void* __restrict__ dnnw, const void* __restrict__ dnnb,
    const void* __restrict__ outw, const void* __restrict__ outb,
    float* __restrict__ ws, __half* __restrict__ whh_h, const int* __restrict__ flagp) {
  int f32 = *flagp;
  __shared__ __align__(16) float lds[1728];   // max CI*9 = 192*9
  int b = blockIdx.x, tid = threadIdx.x;
  if (b < 128)      oc_tr<12>(b, ws + OFF_WT1, cw1, f32, lds, tid);
  else if (b < 292) oc_tr<128>(b - 128, ws + OFF_WT2, cw2, f32, lds, tid);
  else if (b < 484) oc_tr<164>(b - 292, ws + OFF_WT3, cw3, f32, lds, tid);
  else if (b < 676) oc_tr<192>(b - 484, ws + OFF_WT4, cw4, f32, lds, tid);
  else if (b < 804) oc_tr<192>(b - 676, ws + OFF_WT5, cw5, f32, lds, tid);
  else {
    int gid = (b - 804) * 256 + tid;
    const int stride = 64 * 256;
    // w_hh -> f16, rows padded to 256 halves (512 B aligned rows)
    for (int i = gid; i < 250000; i += stride) {
      int row = i / 250, col = i - row * 250;
      whh_h[row * 256 + col] = __float2half(ldf(whh, i, f32));
    }
    cvt_arr(gid, stride, 128, ws + OFF_CB + 0 * 256, cb1, f32);
    cvt_arr(gid, stride, 164, ws + OFF_CB + 1 * 256, cb2, f32);
    cvt_arr(gid, stride, 192, ws + OFF_CB + 2 * 256, cb3, f32);
    cvt_arr(gid, stride, 192, ws + OFF_CB + 3 * 256, cb4, f32);
    cvt_arr(gid, stride, 128, ws + OFF_CB + 4 * 256, cb5, f32);
    cvt_arr(gid, stride, 16384, ws + OFF_DNNW, dnnw, f32);
    cvt_arr(gid, stride, 128, ws + OFF_DNNB, dnnb, f32);
    cvt_arr(gid, stride, 640, ws + OFF_OUTW, outw, f32);
    cvt_arr(gid, stride, 5, ws + OFF_OUTB, outb, f32);
  }
}

// ---------- kernel 2: recurrent LSTM, 4 blocks (sentence x direction) ----------
// 512 threads, 2 gate-rows/thread. amdgpu_waves_per_eu(2,2) forbids >2
// waves/EU -> register budget 512/2 = 256 VGPRs (launch_bounds' 2nd arg is
// only a cap promise; rounds 3/6/7 proved the allocator chases occupancy and
// remats/spills at 64-128 regs). Weight split:
//   k 0..223   : 2 x 28 uint4 = 224 pinned VGPRs (demand ~240 <= 256)
//   k 224..249 : 13 uint/row in LDS wl[13][1000] (52 KB, conflict-free)
// Zero global weight traffic inside the recurrence.
__global__ __launch_bounds__(512)
__attribute__((amdgpu_waves_per_eu(2, 2)))
void k_lstm(const float* __restrict__ P_all, const __half* __restrict__ Wp,
            float* __restrict__ S) {
  __shared__ __align__(16) uint wl[13][1000];   // 52000 B
  __shared__ __align__(16) uint h2[128];        // packed h (125 used)
  __shared__ __align__(16) float gates[1000];   // 4000 B  (total 56.5 KB)
  int tid = threadIdx.x;
  int r = blockIdx.x, s = r >> 1, rev = r & 1;
  bool act = tid < 500;
  int ti = act ? tid : 499;                     // clamp: uniform loads, no OOB
  int row0 = 2 * ti;
  const uint* wr0 = (const uint*)(Wp + row0 * 256);
  const uint* wr1 = (const uint*)(Wp + (row0 + 1) * 256);

  uint4 wA[28], wB[28];                         // k = 0..223 (112 half2/row)
  {
    const uint4* a4 = (const uint4*)wr0;
    const uint4* b4 = (const uint4*)wr1;
#pragma unroll
    for (int j = 0; j < 28; ++j) wA[j] = a4[j];
#pragma unroll
    for (int j = 0; j < 28; ++j) wB[j] = b4[j];
  }
  if (act) {
#pragma unroll
    for (int j = 0; j < 13; ++j) {              // k = 224..249 tail to LDS
      wl[j][row0]     = wr0[112 + j];
      wl[j][row0 + 1] = wr1[112 + j];
    }
  }
#pragma unroll
  for (int j = 0; j < 28; ++j) { keep4(wA[j]); keep4(wB[j]); }

  if (tid < 128) h2[tid] = 0u;
  float c = 0.0f;
  __syncthreads();

  const float* P = P_all + s * 32000;
#pragma unroll 1
  for (int t = 0; t < 32; ++t) {
    int tp = rev ? (31 - t) : t;
    {
      float2 pv = *(const float2*)(P + tp * 1000 + row0);
      float a0 = pv.x, a1 = pv.y;
      const uint4* h4 = (const uint4*)h2;
#pragma unroll
      for (int j = 0; j < 28; ++j) {            // k = 0..223 from pinned VGPRs
        uint4 hv = h4[j];
        a0 = dot2(wA[j].x, hv.x, a0); a1 = dot2(wB[j].x, hv.x, a1);
        a0 = dot2(wA[j].y, hv.y, a0); a1 = dot2(wB[j].y, hv.y, a1);
        a0 = dot2(wA[j].z, hv.z, a0); a1 = dot2(wB[j].z, hv.z, a1);
        a0 = dot2(wA[j].w, hv.w, a0); a1 = dot2(wB[j].w, hv.w, a1);
      }
#pragma unroll
      for (int j = 0; j < 13; ++j) {            // k = 224..249 from LDS
        uint2 wv = *(const uint2*)(&wl[j][row0]);
        uint hh = h2[112 + j];
        a0 = dot2(wv.x, hh, a0);
        a1 = dot2(wv.y, hh, a1);
      }
      if (act) *(float2*)(gates + row0) = make_float2(a0, a1);
    }
    __syncthreads();
    if (tid < 250) {
      float gi = gates[tid], gf = gates[250 + tid];
      float gg = gates[500 + tid], go = gates[750 + tid];
      c = sigm(gf) * c + sigm(gi) * tanhf(gg);
      float hn = sigm(go) * tanhf(c);
      S[(s * 32 + t) * 500 + rev * 250 + tid] = hn;
      float ho = __shfl_down(hn, 1);            // pair (2m, 2m+1) within wave
      if ((tid & 1) == 0) h2[tid >> 1] = pack2(hn, ho);
    }
    __syncthreads();
  }
}

// ---------- kernel 3: similarity cube, one wave per (i,j) ----------
__global__ __launch_bounds__(64) void k_sim(const float* __restrict__ S,
                                            float* __restrict__ SIM) {
  int i = blockIdx.x >> 5, j = blockIdx.x & 31, l = threadIdx.x;
  const float* a = S + i * 500;
  const float* bv = S + 16000 + j * 500;
  float d[10];
#pragma unroll
  for (int v = 0; v < 10; ++v) d[v] = 0.0f;
  for (int k = l; k < 250; k += 64) {
    float af = a[k], ab = a[250 + k], bf = bv[k], bb = bv[250 + k];
    d[0] = fmaf(af, bf, d[0]);  d[1] = fmaf(ab, bb, d[1]);
    d[2] = fmaf(af, bb, d[2]);  d[3] = fmaf(ab, bf, d[3]);
    d[4] = fmaf(af, af, d[4]);  d[5] = fmaf(ab, ab, d[5]);
    d[6] = fmaf(af, ab, d[6]);  d[7] = fmaf(bf, bf, d[7]);
    d[8] = fmaf(bb, bb, d[8]);  d[9] = fmaf(bf, bb, d[9]);
  }
#pragma unroll
  for (int v = 0; v < 10; ++v)
    for (int off = 32; off > 0; off >>= 1) d[v] += __shfl_down(d[v], off);
  if (l == 0) {
    float dff = d[0], dbb = d[1], dfb = d[2], dbf = d[3];
    float nf1 = d[4], nb1 = d[5], c1 = d[6], nf2 = d[7], nb2 = d[8], c2 = d[9];
    int p = i * 32 + j;
    float dot = dff + dbb, n1f = nf1 + nb1, n2f = nf2 + nb2;
    SIM[0 * 1024 + p] = dot;
    SIM[1 * 1024 + p] = dot / (sqrtf(n1f) * sqrtf(n2f) + 1e-8f);
    SIM[2 * 1024 + p] = sqrtf(fmaxf(n1f + n2f - 2.0f * dot, 0.0f));
    SIM[3 * 1024 + p] = dff;
    SIM[4 * 1024 + p] = dff / (sqrtf(nf1) * sqrtf(nf2) + 1e-8f);
    SIM[5 * 1024 + p] = sqrtf(fmaxf(nf1 + nf2 - 2.0f * dff, 0.0f));
    SIM[6 * 1024 + p] = dbb;
    SIM[7 * 1024 + p] = dbb / (sqrtf(nb1) * sqrtf(nb2) + 1e-8f);
    SIM[8 * 1024 + p] = sqrtf(fmaxf(nb1 + nb2 - 2.0f * dbb, 0.0f));
    float dsum = dff + dbb + dfb + dbf;
    float ns1 = n1f + 2.0f * c1, ns2 = n2f + 2.0f * c2;
    SIM[9 * 1024 + p] = dsum;
    SIM[10 * 1024 + p] = dsum / (sqrtf(ns1) * sqrtf(ns2) + 1e-8f);
    SIM[11 * 1024 + p] = sqrtf(fmaxf(ns1 + ns2 - 2.0f * dsum, 0.0f));
  }
}

// ---------- kernel 4: top-64 greedy match (both channels in one sort cadence) ----------
__global__ __launch_bounds__(1024) void k_greedy(const float* __restrict__ SIM,
                                                 float* __restrict__ A0) {
  __shared__ ull keys0[1024], keys1[1024];
  __shared__ unsigned char sel[1024];
  int t = threadIdx.x;
  sel[t] = 0;
  {
    float v0 = SIM[9 * 1024 + t], v1 = SIM[10 * 1024 + t];
    uint u0 = __float_as_uint(v0);
    u0 = (u0 & 0x80000000u) ? ~u0 : (u0 | 0x80000000u);
    uint u1 = __float_as_uint(v1);
    u1 = (u1 & 0x80000000u) ? ~u1 : (u1 | 0x80000000u);
    keys0[t] = (((ull)u0) << 32) | (uint)(1023 - t);
    keys1[t] = (((ull)u1) << 32) | (uint)(1023 - t);
  }
  __syncthreads();
  for (int k = 2; k <= 1024; k <<= 1) {
    for (int j = k >> 1; j > 0; j >>= 1) {
      int ixj = t ^ j;
      if (ixj > t) {
        bool desc = ((t & k) == 0);
        ull a = keys0[t], b2 = keys0[ixj];
        if ((a < b2) == desc) { keys0[t] = b2; keys0[ixj] = a; }
        ull c2 = keys1[t], d2 = keys1[ixj];
        if ((c2 < d2) == desc) { keys1[t] = d2; keys1[ixj] = c2; }
      }
      __syncthreads();
    }
  }
  if (t == 0 || t == 512) {                       // two serial greedies, parallel waves
    const ull* ks = (t == 0) ? keys0 : keys1;
    uint m1 = 0, m2 = 0;
    for (int n = 0; n < 64; ++n) {
      int flat = 1023 - (int)(ks[n] & 0xFFFFFFFFu);
      int p1 = flat >> 5, p2 = flat & 31;
      if (!((m1 >> p1) & 1u) && !((m2 >> p2) & 1u)) {
        m1 |= 1u << p1; m2 |= 1u << p2; sel[flat] = 1;   // benign same-value race
      }
    }
  }
  __syncthreads();
  float fac = sel[t] ? 1.0f : 0.1f;
#pragma unroll
  for (int cidx = 0; cidx < 12; ++cidx)
    A0[t * 12 + cidx] = SIM[cidx * 1024 + t] * fac;  // channels-last [i][j][c]
}

// ---------- conv kernels (channels-last, fused relu+2x2 maxpool) ----------
template <int CIN, int CP, int COUT, int WIN, int TILESX, int G>
__global__ __launch_bounds__(256) void k_conv_tiled(
    const float* __restrict__ in, const float* __restrict__ wt,
    const float* __restrict__ bias, float* __restrict__ out) {
  __shared__ __align__(16) float lin[100 * CP];  // 10x10 halo tile
  __shared__ float pbuf[G * 64];
  int tid = threadIdx.x, b = blockIdx.x;
  const int TILES = TILESX * TILESX;
  int tile = b % TILES, ocg = b / TILES;
  int ty = tile / TILESX, tx = tile % TILESX;
  int oc0 = ocg * G;
  const int NQ = 25 * CIN;
  for (int m = tid; m < NQ; m += 256) {
    int pxy = m / (CIN / 4), cq = m - pxy * (CIN / 4);
    int py = pxy / 10, px = pxy - py * 10;
    int gy = ty * 8 + py - 1, gx = tx * 8 + px - 1;
    float4 v = make_float4(0.f, 0.f, 0.f, 0.f);
    if (gy >= 0 && gy < WIN && gx >= 0 && gx < WIN)
      v = *(const float4*)(in + (gy * WIN + gx) * CIN + 4 * cq);
    *(float4*)(lin + (py * 10 + px) * CP + 4 * cq) = v;
  }
  __syncthreads();
  int px = tid & 63, ocl = tid >> 6;
  int py2 = px >> 3, px2 = px & 7;
  const int G4 = G / 4;
  float acc[G4];
  int ocw[G4];
#pragma unroll
  for (int m = 0; m < G4; ++m) {
    int oc = oc0 + ocl + 4 * m;
    ocw[m] = (oc < COUT) ? oc : (COUT - 1);
    acc[m] = (oc < COUT) ? bias[oc] : 0.0f;
  }
#pragma unroll
  for (int tap = 0; tap < 9; ++tap) {
    int ky = tap / 3, kx = tap % 3;
    const float* ibase = lin + ((py2 + ky) * 10 + (px2 + kx)) * CP;
#pragma unroll 4
    for (int cq = 0; cq < CIN / 4; ++cq) {
      float4 iv = *(const float4*)(ibase + 4 * cq);
#pragma unroll
      for (int m = 0; m < G4; ++m) {
        float4 wv = *(const float4*)(wt + (ocw[m] * 9 + tap) * CIN + 4 * cq);
        acc[m] = fmaf(iv.x, wv.x, fmaf(iv.y, wv.y, fmaf(iv.z, wv.z, fmaf(iv.w, wv.w, acc[m]))));
      }
    }
  }
#pragma unroll
  for (int m = 0; m < G4; ++m)
    pbuf[(ocl + 4 * m) * 64 + px] = fmaxf(acc[m], 0.0f);
  __syncthreads();
  if (tid < G * 16) {
    int ocl2 = tid >> 4, q = tid & 15;
    int qy = q >> 2, qx = q & 3;
    const float* pb = pbuf + ocl2 * 64 + qy * 16 + qx * 2;
    float v = fmaxf(fmaxf(pb[0], pb[1]), fmaxf(pb[8], pb[9]));
    int oc = oc0 + ocl2;
    if (oc < COUT) {
      int gy = ty * 4 + qy, gx = tx * 4 + qx;
      out[(gy * (WIN / 2) + gx) * COUT + oc] = v;
    }
  }
}

template <int CIN, int CP, int COUT, int HW, int G>
__global__ __launch_bounds__(256) void k_conv_small(
    const float* __restrict__ in, const float* __restrict__ wt,
    const float* __restrict__ bias, float* __restrict__ out) {
  __shared__ __align__(16) float lin[HW * HW * CP];
  __shared__ float pbuf[G * HW * HW];
  int tid = threadIdx.x;
  int oc0 = blockIdx.x * G;
  const int NPX = HW * HW;
  const int NQ = NPX * CIN / 4;
  for (int m = tid; m < NQ; m += 256) {
    int pxy = m / (CIN / 4), cq = m - pxy * (CIN / 4);
    float4 v = *(const float4*)(in + pxy * CIN + 4 * cq);
    *(float4*)(lin + pxy * CP + 4 * cq) = v;
  }
  __syncthreads();
  int px = tid % NPX, ocl = tid / NPX;
  int py = px / HW, pxx = px % HW;
  int oc = oc0 + ocl;
  float acc = bias[oc];
#pragma unroll
  for (int tap = 0; tap < 9; ++tap) {
    int yy = py + tap / 3 - 1, xx = pxx + tap % 3 - 1;
    if (yy >= 0 && yy < HW && xx >= 0 && xx < HW) {
      const float* ibase = lin + (yy * HW + xx) * CP;
      const float* wbase = wt + (oc * 9 + tap) * CIN;
#pragma unroll 4
      for (int cq = 0; cq < CIN / 4; ++cq) {
        float4 iv = *(const float4*)(ibase + 4 * cq);
        float4 wv = *(const float4*)(wbase + 4 * cq);
        acc = fmaf(iv.x, wv.x, fmaf(iv.y, wv.y, fmaf(iv.z, wv.z, fmaf(iv.w, wv.w, acc))));
      }
    }
  }
  pbuf[ocl * NPX + px] = fmaxf(acc, 0.0f);
  __syncthreads();
  const int HW2 = HW / 2;
  if (tid < G * HW2 * HW2) {
    int ocl2 = tid / (HW2 * HW2), q = tid % (HW2 * HW2);
    int qy = q / HW2, qx = q % HW2;
    const float* pb = pbuf + ocl2 * NPX + (2 * qy) * HW + 2 * qx;
    float v = fmaxf(fmaxf(pb[0], pb[1]), fmaxf(pb[HW], pb[HW + 1]));
    out[(qy * HW2 + qx) * COUT + oc0 + ocl2] = v;
  }
}

// ---------- kernel 10: dense head ----------
__global__ __launch_bounds__(256) void k_fc(
    const float* __restrict__ A5,
    const float* __restrict__ dnnw, const float* __restrict__ dnnb,
    const float* __restrict__ outw, const float* __restrict__ outb,
    const int* __restrict__ flagp, void* __restrict__ outp) {
  __shared__ __align__(16) float v[128], u[128];
  int t = threadIdx.x;
  if (t < 128) v[t] = A5[t];
  __syncthreads();
  if (t < 128) {
    float acc = dnnb[t];
    const float* wr = dnnw + t * 128;
#pragma unroll 8
    for (int k = 0; k < 128; ++k) acc = fmaf(wr[k], v[k], acc);
    u[t] = fmaxf(acc, 0.0f);
  }
  __syncthreads();
  if (t < 5) {
    float acc = outb[t];
    const float* wr = outw + t * 128;
#pragma unroll 8
    for (int k = 0; k < 128; ++k) acc = fmaf(wr[k], u[k], acc);
    if (*flagp) ((float*)outp)[t] = acc;
    else ((__hip_bfloat16*)outp)[t] = __float2bfloat16(acc);
  }
}

// ---------- launch ----------
extern "C" void kernel_launch(void* const* d_in, const int* in_sizes, int n_in,
                              void* d_out, int out_size, void* d_ws, size_t ws_size,
                              hipStream_t stream) {
  const int* x1 = (const int*)d_in[0];
  const int* x2 = (const int*)d_in[1];

  float* ws = (float*)d_ws;
  __half* whh_h = (__half*)(ws + OFF_WHH);
  int* flagp = (int*)(ws + OFF_FLAG);

  k_mode<<<1, 1024, 0, stream>>>((const uint4*)d_in[4], flagp);
  k_pgemm<<<125, 256, 0, stream>>>(x1, x2, d_in[2], d_in[3], d_in[5], d_in[6],
                                   ws + OFF_P, flagp);
  k_pwt<<<868, 256, 0, stream>>>(d_in[4],
      d_in[7], d_in[9], d_in[11], d_in[13], d_in[15],
      d_in[8], d_in[10], d_in[12], d_in[14], d_in[16],
      d_in[17], d_in[18], d_in[19], d_in[20],
      ws, whh_h, flagp);
  k_lstm<<<4, 512, 0, stream>>>(ws + OFF_P, whh_h, ws + OFF_S);
  k_sim<<<1024, 64, 0, stream>>>(ws + OFF_S, ws + OFF_SIM);
  k_greedy<<<1, 1024, 0, stream>>>(ws + OFF_SIM, ws + OFF_A0);
  k_conv_tiled<12, 12, 128, 32, 4, 8><<<256, 256, 0, stream>>>(ws + OFF_A0, ws + OFF_WT1, ws + OFF_CB + 0 * 256, ws + OFF_A1);
  k_conv_tiled<128, 132, 164, 16, 2, 8><<<84, 256, 0, stream>>>(ws + OFF_A1, ws + OFF_WT2, ws + OFF_CB + 1 * 256, ws + OFF_A2);
  k_conv_small<164, 164, 192, 8, 4><<<48, 256, 0, stream>>>(ws + OFF_A2, ws + OFF_WT3, ws + OFF_CB + 2 * 256, ws + OFF_A3);
  k_conv_small<192, 196, 192, 4, 16><<<12, 256, 0, stream>>>(ws + OFF_A3, ws + OFF_WT4, ws + OFF_CB + 3 * 256, ws + OFF_A4);
  k_conv_small<192, 196, 128, 2, 64><<<2, 256, 0, stream>>>(ws + OFF_A4, ws + OFF_WT5, ws + OFF_CB + 4 * 256, ws + OFF_A5);
  k_fc<<<1, 256, 0, stream>>>(ws + OFF_A5, ws + OFF_DNNW, ws + OFF_DNNB,
                              ws + OFF_OUTW, ws + OFF_OUTB, flagp, d_out);
}